// Round 6
// baseline (211.882 us; speedup 1.0000x reference)
//
#include <hip/hip_runtime.h>

// LocallyConnected1d via bf16 MFMA: out[b,o,l] = sum_{i,k} x[b,i,l+k-4]*w[i,o,k,l] + bias[o,l]
//
// R14: DIAGNOSTIC DECOMPOSITION (skill rule: ablate before optimizing; 6
// structural theories falsified R9-R13 with dur pinned at ~47us and all
// pipes <35% busy). Four dispatches, per-dispatch durs read from rocprof:
//   D0 wprobe      : weight stream alone (same addressing/ring/pacing,
//                    no LDS/barrier/MFMA). Clean ~11-16us; >=30us => the
//                    16x64B-segment pattern is the wall -> pre-transpose.
//   D1 <NOW=1>     : weights pinned to step-0 tile (L2-hit); isolates
//                    "everything except the weight stream".
//   D2 <NOX=1>     : x global loads removed; isolates stage episodes.
//   D3 <0,0>       : exact R10 kernel, fully overwrites d_out -> correct.
// D1/D2 write garbage to d_out first; D3 rewrites every (b,o,l). No sync,
// no alloc: graph-capture safe. Total reported dur ~= sum (~150us) -- this
// round buys data, not score.

#define CIN   64
#define COUT  64
#define SEQ   512
#define KS    9
#define LT    16
#define OT    8
#define LWIN  24
#define WSTR  (COUT*KS*SEQ)            // weight i-stride (floats)
#define XBS   40                       // Xs b-stride (ush)
#define XLW   (64*XBS)                 // Xs lw-stride = 2560 ush
#define XS_ELEMS (LWIN*XLW)            // 61440 ush = 120 KB
#define BOS   40                       // Bs o-stride (ush)
#define BLS   328                      // Bs l-stride (ush)
#define BSLOT (LT*BLS)                 // 5248 ush per buffer
#define ZOFF  (XS_ELEMS + 2*BSLOT)     // zero region for n>=8 B-frag reads
#define LDS_USH (ZOFF + 64)            // 72000 ush
#define LDS_BYTES (LDS_USH*2)          // 144000 B -> 1 block/CU
#define NSTEP 18                       // 2 i-halves x 9 k-taps

typedef __attribute__((ext_vector_type(8))) short bf16x8;
typedef __attribute__((ext_vector_type(4))) float f32x4;

__device__ __forceinline__ uint pack2bf(float a0, float a1) {
    uint u0 = __float_as_uint(a0) + 0x8000u;
    uint u1 = __float_as_uint(a1) + 0x8000u;
    return __builtin_amdgcn_perm(u1, u0, 0x07060302);  // (bf(a1)<<16)|bf(a0)
}

// Relaxed barrier: drain LDS only; global loads stay in flight across it.
#define BAR() do {                                                           \
    asm volatile("s_waitcnt lgkmcnt(0)" ::: "memory");                       \
    __builtin_amdgcn_s_barrier();                                            \
    asm volatile("" ::: "memory");                                           \
} while (0)

// ---------------- D0: weight-stream probe ----------------
// Identical stager addressing and 3-slot ring pacing as the real kernel;
// consume = register sum (forces the same vmcnt waits WRITE_BS would).
__global__ __launch_bounds__(1024, 4)
void wprobe(const float* __restrict__ w)
{
    const int tid = threadIdx.x;
    if (tid >= 512) return;
    const int lt = blockIdx.x >> 3;
    const int os = blockIdx.x & 7;
    const int l0 = lt * LT, o0 = os * OT;
    const int lf  = tid & 3;
    const int oo  = (tid >> 2) & 7;
    const int ipp = (tid >> 5) & 15;
    const float* wbase = w + ((size_t)(2*ipp)*COUT + (o0 + oo))*(KS*SEQ) + l0 + lf*4;

    float4 rA[3], rB[3];
    float4 acc = make_float4(0.f, 0.f, 0.f, 0.f);
    #define PLOAD(sl, s) {                                                       \
        const int ih_ = (s) / 9, k_ = (s) % 9;                                   \
        const float* p_ = wbase + (size_t)ih_*32*WSTR + k_*SEQ;                  \
        rA[sl] = *(const float4*)p_;                                             \
        rB[sl] = *(const float4*)(p_ + WSTR);                                    \
    }
    PLOAD(0, 0) PLOAD(1, 1) PLOAD(2, 2)
    #pragma unroll
    for (int s = 0; s < NSTEP; ++s) {
        const int c = s % 3;
        acc.x += rA[c].x + rB[c].x;  acc.y += rA[c].y + rB[c].y;
        acc.z += rA[c].z + rB[c].z;  acc.w += rA[c].w + rB[c].w;
        if (s + 3 < NSTEP) PLOAD(c, s + 3)
    }
    asm volatile("" :: "v"(acc.x), "v"(acc.y), "v"(acc.z), "v"(acc.w));
}

// ---------------- D1/D2/D3: R10 kernel, templated ablations ----------------
// NOW=1: every step loads the step-0 weight tile (L2-hit; same instrs/waits).
// NOX=1: x global loads removed (pack + ds_writes of zeros kept).
template<int NOW, int NOX>
__global__ __launch_bounds__(1024, 4)
void lc1d_mfma(const float* __restrict__ x, const float* __restrict__ w,
               const float* __restrict__ bias, float* __restrict__ out)
{
    extern __shared__ ushort lds[];
    ushort* Xs = lds;                    // [lw 0..23][b 0..63][ii 0..31]
    ushort* BsB = lds + XS_ELEMS;        // 2 x [l 0..15][o 0..7][kk 0..31]

    const int tid  = threadIdx.x;
    const int lane = tid & 63;
    const int wvid = tid >> 6;           // 0..15
    const int bt = wvid & 3;
    const int lg = wvid >> 2;
    const int lt = blockIdx.x >> 3;
    const int os = blockIdx.x & 7;
    const int l0 = lt * LT;
    const int o0 = os * OT;

    const bool stager = (tid < 512);
    const int lf  = tid & 3;
    const int oo  = (tid >> 2) & 7;
    const int ipp = (tid >> 5) & 15;

    const float* wbase = w + ((size_t)(2*ipp)*COUT + (o0 + oo))*(KS*SEQ) + l0 + lf*4;

    float4 rA[3], rB[3];

    #define LOAD_RING(sl, s) if (stager && (s) < NSTEP) {                        \
        const int ih_ = NOW ? 0 : (s) / 9;                                       \
        const int k_  = NOW ? 0 : (s) % 9;                                       \
        const float* p_ = wbase + (size_t)ih_*32*WSTR + k_*SEQ;                  \
        rA[sl] = *(const float4*)p_;                                             \
        rB[sl] = *(const float4*)(p_ + WSTR);                                    \
    }

    #define WRITE_BS(sl, s) if (stager) {                                        \
        ushort* dst_ = BsB + ((s)&1)*BSLOT + oo*BOS + 2*ipp;                     \
        _Pragma("unroll")                                                        \
        for (int dl = 0; dl < 4; ++dl) {                                         \
            uint pk_ = pack2bf((&rA[sl].x)[dl], (&rB[sl].x)[dl]);                \
            *(uint*)(dst_ + (lf*4+dl)*BLS) = pk_;                                \
        }                                                                        \
    }

    #define STAGE_XS(ih) {                                                       \
        const int qq  = tid & 7;                                                 \
        const int rp0 = tid >> 3;                                                \
        if (qq < 6) {                                                            \
            _Pragma("unroll")                                                    \
            for (int it = 0; it < 8; ++it) {                                     \
                const int rp = rp0 + it*128;                                     \
                const int b_ = rp >> 4, ip_ = rp & 15;                           \
                const float* s0 = x + ((size_t)(b_*CIN) + (ih)*32 + 2*ip_)*SEQ   \
                                    + (l0 - 4) + qq*4;                           \
                float4 v0 = make_float4(0.f,0.f,0.f,0.f), v1 = v0;               \
                if ((!NOX) &&                                                    \
                    !((lt == 0 && qq == 0) || (lt == 31 && qq == 5))) {          \
                    v0 = *(const float4*)s0;                                     \
                    v1 = *(const float4*)(s0 + SEQ);                             \
                }                                                                \
                ushort* d_ = Xs + b_*XBS + 2*ip_;                                \
                _Pragma("unroll")                                                \
                for (int dl = 0; dl < 4; ++dl)                                   \
                    *(uint*)(d_ + (qq*4+dl)*XLW) = pack2bf((&v0.x)[dl],          \
                                                           (&v1.x)[dl]);         \
            }                                                                    \
        }                                                                        \
    }

    const int aoff = (bt*16 + (lane & 15))*XBS + (lane >> 4)*8;
    const int boff = (lane & 15)*BOS + (lane >> 4)*8;
    const bool nhi = (lane & 15) >= 8;
    const ushort* zptr = lds + ZOFF + (lane >> 4)*8;

    f32x4 acc[4];
    #pragma unroll
    for (int j = 0; j < 4; ++j) acc[j] = (f32x4)0.0f;

    #define DO_MFMA(s) {                                                         \
        const int k_ = (s) % 9;                                                  \
        const ushort* BsS = BsB + ((s)&1)*BSLOT;                                 \
        _Pragma("unroll")                                                        \
        for (int dl = 0; dl < 4; ++dl) {                                         \
            const int ll = lg*4 + dl;                                            \
            bf16x8 Af = *(const bf16x8*)(Xs + (ll + k_)*XLW + aoff);             \
            const ushort* Bp = nhi ? zptr : (BsS + ll*BLS + boff);               \
            bf16x8 Bf = *(const bf16x8*)Bp;                                      \
            acc[dl] = __builtin_amdgcn_mfma_f32_16x16x32_bf16(Af, Bf, acc[dl],   \
                                                              0, 0, 0);          \
        }                                                                        \
    }

    #define STEP(s) {                                                            \
        if ((s) < NSTEP-1) WRITE_BS(((s)+1)%3, (s)+1)                            \
        LOAD_RING(((s)+1)%3, (s)+4)                                              \
        DO_MFMA(s)                                                               \
        BAR();                                                                   \
    }

    LOAD_RING(0, 0)
    LOAD_RING(1, 1)
    LOAD_RING(2, 2)
    if (tid < 64) lds[ZOFF + tid] = 0;
    STAGE_XS(0)
    WRITE_BS(0, 0)
    LOAD_RING(0, 3)
    BAR();

    STEP(0)  STEP(1)  STEP(2)  STEP(3)  STEP(4)
    STEP(5)  STEP(6)  STEP(7)  STEP(8)

    STAGE_XS(1)
    BAR();

    STEP(9)  STEP(10) STEP(11) STEP(12) STEP(13)
    STEP(14) STEP(15) STEP(16) STEP(17)

    if (!nhi) {
        const int og = o0 + (lane & 15);
        const int rb = (lane >> 4)*4;
        #pragma unroll
        for (int dl = 0; dl < 4; ++dl) {
            const int lgl = l0 + lg*4 + dl;
            const float bv = bias[og*SEQ + lgl];
            #pragma unroll
            for (int r = 0; r < 4; ++r) {
                const int bg = bt*16 + rb + r;
                out[((size_t)(bg*COUT + og))*SEQ + lgl] = acc[dl][r] + bv;
            }
        }
    }
}

extern "C" void kernel_launch(void* const* d_in, const int* in_sizes, int n_in,
                              void* d_out, int out_size, void* d_ws, size_t ws_size,
                              hipStream_t stream) {
    const float* x    = (const float*)d_in[0];
    const float* wgt  = (const float*)d_in[1];
    const float* bias = (const float*)d_in[2];
    float* out        = (float*)d_out;

    auto kNW = lc1d_mfma<1,0>;
    auto kNX = lc1d_mfma<0,1>;
    auto kRL = lc1d_mfma<0,0>;
    hipFuncSetAttribute((const void*)kNW,
                        hipFuncAttributeMaxDynamicSharedMemorySize, LDS_BYTES);
    hipFuncSetAttribute((const void*)kNX,
                        hipFuncAttributeMaxDynamicSharedMemorySize, LDS_BYTES);
    hipFuncSetAttribute((const void*)kRL,
                        hipFuncAttributeMaxDynamicSharedMemorySize, LDS_BYTES);

    dim3 grid(256);
    // D0: weight stream alone
    wprobe<<<grid, 1024, 0, stream>>>(wgt);
    // D1: no weight stream (L2-resident step-0 tile) -- garbage out, overwritten
    kNW<<<grid, 1024, LDS_BYTES, stream>>>(x, wgt, bias, out);
    // D2: no x loads -- garbage out, overwritten
    kNX<<<grid, 1024, LDS_BYTES, stream>>>(x, wgt, bias, out);
    // D3: real R10 kernel -- writes every output element, final answer
    kRL<<<grid, 1024, LDS_BYTES, stream>>>(x, wgt, bias, out);
}

// Round 7
// 133.611 us; speedup vs baseline: 1.5858x; 1.5858x over previous
//
#include <hip/hip_runtime.h>

// LocallyConnected1d via bf16 MFMA: out[b,o,l] = sum_{i,k} x[b,i,l+k-4]*w[i,o,k,l] + bias[o,l]
// 512 per-l GEMMs (M=b=64, N=o (8 real, 8 zero-padded), K=576 k-major).
//
// R15: hand-paced weight ring (R14 decomposition: weight stream alone is
// fast, structure alone is fast, combination = 47us. Cause: the load->rA->
// WRITE_BS chain is register-carried, so the compiler inserts its own vmcnt
// wait at the use; any inline asm w/ memory clobber (BAR) resets its counter
// tracking -> conservative vmcnt(0) EVERY step. The 3-slot ring never existed
// in hardware: 18 full HBM drains = ~47us. Same with __syncthreads (R8).)
//  * Ring loads are inline-asm global_load_dwordx4 (invisible to the
//    compiler's waitcnt pass -> it inserts no vmem waits in the loop).
//  * Manual s_waitcnt vmcnt(4) + sched_barrier(0) before each WRITE_BS
//    (rule #18: sched_barrier stops reg-only pack/ds_write hoisting above
//    the wait). Pairs are consumed 3 steps after issue; never drained.
//    Tail: vmcnt(2) at step 15, vmcnt(0) at step 16.
//  * Ledger (per stager thread, 2 asm loads/step): steady outstanding = 6
//    (pairs s+1,s+2,s+3); WAITV(4) releases exactly pair s+1. Prologue and
//    mid-boundary x-episodes drain via FIFO (their compiler-inserted waits
//    are younger) -- one-time refill bubbles, ledger stays correct for both
//    x-loading (qq<6) and non-x (qq>=6) stager threads.
//  * Base = R10 schedule (18 single-tap steps, 3-slot ring, lgkm-only BAR)
//    + R12's verified stage-rotation (XBS 40, conflicts 6.0M->3.5M).

#define CIN   64
#define COUT  64
#define SEQ   512
#define KS    9
#define LT    16
#define OT    8
#define LWIN  24
#define WSTR  (COUT*KS*SEQ)            // weight i-stride (floats)
#define XBS   40                       // Xs b-stride (ush): 32 i + 8 pad
#define XLW   (64*XBS)                 // Xs lw-stride = 2560 ush
#define XS_ELEMS (LWIN*XLW)            // 61440 ush = 120 KB
#define BOS   40                       // Bs o-stride (ush)
#define BLS   328                      // Bs l-stride (ush)
#define BSLOT (LT*BLS)                 // 5248 ush per buffer
#define ZOFF  (XS_ELEMS + 2*BSLOT)     // zero region for n>=8 B-frag reads
#define LDS_USH (ZOFF + 64)            // 72000 ush
#define LDS_BYTES (LDS_USH*2)          // 144000 B -> 1 block/CU
#define NSTEP 18                       // 2 i-halves x 9 k-taps

typedef __attribute__((ext_vector_type(8))) short bf16x8;
typedef __attribute__((ext_vector_type(4))) float f32x4;

__device__ __forceinline__ uint pack2bf(float a0, float a1) {
    uint u0 = __float_as_uint(a0) + 0x8000u;
    uint u1 = __float_as_uint(a1) + 0x8000u;
    return __builtin_amdgcn_perm(u1, u0, 0x07060302);  // (bf(a1)<<16)|bf(a0)
}

// Relaxed barrier: drain LDS only; asm ring loads stay in flight across it.
#define BAR() do {                                                           \
    asm volatile("s_waitcnt lgkmcnt(0)" ::: "memory");                       \
    __builtin_amdgcn_s_barrier();                                            \
    asm volatile("" ::: "memory");                                           \
} while (0)

// Manual counted vmem wait. sched_barrier(0) (rule #18): without it the
// compiler hoists register-only v_perm packs above the waitcnt.
#define WAITV(n) do {                                                        \
    asm volatile("s_waitcnt vmcnt(" #n ")" ::: "memory");                    \
    __builtin_amdgcn_sched_barrier(0);                                       \
} while (0)

__global__ __launch_bounds__(1024, 4)
void lc1d_mfma(const float* __restrict__ x, const float* __restrict__ w,
               const float* __restrict__ bias, float* __restrict__ out)
{
    extern __shared__ ushort lds[];
    ushort* Xs = lds;                    // [lw 0..23][b 0..63][ks-rotated 32 + pad]
    ushort* BsB = lds + XS_ELEMS;        // 2 x [l 0..15][o 0..7][kk 0..31]

    const int tid  = threadIdx.x;
    const int lane = tid & 63;
    const int wvid = tid >> 6;           // 0..15
    const int bt = wvid & 3;             // wave's b-tile (16 b)
    const int lg = wvid >> 2;            // wave's l-group (4 l)
    const int lt = blockIdx.x >> 3;      // 0..31
    const int os = blockIdx.x & 7;       // 0..7 == XCD id
    const int l0 = lt * LT;
    const int o0 = os * OT;

    // ---- weight stager mapping (tid < 512): 64-B-contiguous l spans ----
    const bool stager = (tid < 512);
    const int lf  = tid & 3;             // float4 within the 16-l span
    const int oo  = (tid >> 2) & 7;      // o
    const int ipp = (tid >> 5) & 15;     // i-pair within 32-i half

    const float* wbase = w + ((size_t)(2*ipp)*COUT + (o0 + oo))*(KS*SEQ) + l0 + lf*4;

    f32x4 rA[3], rB[3];                  // 3-slot ring, i-pair per slot

    // step s: ih = s/9 (i-half), k = s%9 (tap). Loads are inline asm:
    // invisible to SIInsertWaitcnts -> no compiler vmem waits in the loop.
    #define LOAD_RING(sl, s) if (stager && (s) < NSTEP) {                        \
        const int ih_ = (s) / 9, k_ = (s) - 9*((s)/9);                           \
        const float* pA_ = wbase + (size_t)ih_*32*WSTR + k_*SEQ;                 \
        const float* pB_ = pA_ + WSTR;                                           \
        asm volatile("global_load_dwordx4 %0, %1, off"                           \
                     : "=&v"(rA[sl]) : "v"(pA_));                                \
        asm volatile("global_load_dwordx4 %0, %1, off"                           \
                     : "=&v"(rB[sl]) : "v"(pB_));                                \
    }

    // transpose+cvt ring slot -> Bs parity (s&1): b32 of i-pair at [l][o][kk]
    #define WRITE_BS(sl, s) {                                                    \
        ushort* dst_ = BsB + ((s)&1)*BSLOT + oo*BOS + 2*ipp;                     \
        _Pragma("unroll")                                                        \
        for (int dl = 0; dl < 4; ++dl) {                                         \
            uint pk_ = pack2bf(rA[sl][dl], rB[sl][dl]);                          \
            *(uint*)(dst_ + (lf*4+dl)*BLS) = pk_;                                \
        }                                                                        \
    }

    // stage Xs for i-half ih: Xs[lw][b][rot(ii)] = bf16(x[b, ih*32+ii, l0-4+lw])
    // rot (R12): row lw = qq*4+dl keeps its four 8-ush ks-groups rotated by
    // qq&3 = (row>>2)&3, matching the read-side col formula below.
    // x loads stay IR-level: their compiler waits are FIFO-younger than the
    // ring pairs, so episodes drain the ring once (bubble, not a hazard).
    #define STAGE_XS(ih) {                                                       \
        const int qq  = tid & 7;                                                 \
        const int rp0 = tid >> 3;                                                \
        const int cr_ = (qq & 3) << 3;                                           \
        if (qq < 6) {                                                            \
            _Pragma("unroll")                                                    \
            for (int it = 0; it < 8; ++it) {                                     \
                const int rp = rp0 + it*128;                                     \
                const int b_ = rp >> 4, ip_ = rp & 15;                           \
                const float* s0 = x + ((size_t)(b_*CIN) + (ih)*32 + 2*ip_)*SEQ   \
                                    + (l0 - 4) + qq*4;                           \
                float4 v0 = make_float4(0.f,0.f,0.f,0.f), v1 = v0;               \
                if (!((lt == 0 && qq == 0) || (lt == 31 && qq == 5))) {          \
                    v0 = *(const float4*)s0;                                     \
                    v1 = *(const float4*)(s0 + SEQ);                             \
                }                                                                \
                ushort* d_ = Xs + b_*XBS + ((2*ip_ + cr_) & 31);                 \
                _Pragma("unroll")                                                \
                for (int dl = 0; dl < 4; ++dl)                                   \
                    *(uint*)(d_ + (qq*4+dl)*XLW) = pack2bf((&v0.x)[dl],          \
                                                           (&v1.x)[dl]);         \
            }                                                                    \
        }                                                                        \
    }

    // MFMA lane constants
    const int abase = (bt*16 + (lane & 15))*XBS;
    const int ks_   = lane >> 4;
    const int boff  = (lane & 15)*BOS + ks_*8;
    const bool nhi  = (lane & 15) >= 8;                // dead o lanes -> zeros
    const ushort* zptr = lds + ZOFF + ks_*8;           // broadcast zeros

    f32x4 acc[4];
    #pragma unroll
    for (int j = 0; j < 4; ++j) acc[j] = (f32x4)0.0f;

    // gather-then-MFMA (one lgkm wait cluster instead of four)
    #define DO_MFMA(s) {                                                         \
        const int k_ = (s) % 9;                                                  \
        const ushort* BsS = BsB + ((s)&1)*BSLOT;                                 \
        bf16x8 Af[4], Bf[4];                                                     \
        _Pragma("unroll")                                                        \
        for (int dl = 0; dl < 4; ++dl) {                                         \
            const int ll  = lg*4 + dl;                                           \
            const int row = ll + k_;                                             \
            const int col = ((ks_ + (row >> 2)) & 3) << 3;                       \
            Af[dl] = *(const bf16x8*)(Xs + row*XLW + abase + col);               \
            Bf[dl] = *(const bf16x8*)(nhi ? zptr : (BsS + ll*BLS + boff));       \
        }                                                                        \
        _Pragma("unroll")                                                        \
        for (int dl = 0; dl < 4; ++dl)                                           \
            acc[dl] = __builtin_amdgcn_mfma_f32_16x16x32_bf16(Af[dl], Bf[dl],    \
                                                              acc[dl], 0, 0, 0); \
    }

    // one barrier per step; during step s, stagers fill Bs parity (s+1)&1
    // from the pair issued 3 steps ago, released by exactly vmcnt(wv).
    #define STEP(s, wv) {                                                        \
        if (stager && (s) < NSTEP-1) {                                           \
            WAITV(wv);                                                           \
            WRITE_BS(((s)+1)%3, (s)+1)                                           \
        }                                                                        \
        LOAD_RING(((s)+1)%3, (s)+4)                                              \
        DO_MFMA(s)                                                               \
        BAR();                                                                   \
    }

    // ---- prologue ----
    LOAD_RING(0, 0)
    LOAD_RING(1, 1)
    LOAD_RING(2, 2)
    if (tid < 64) lds[ZOFF + tid] = 0;
    STAGE_XS(0)
    if (stager) {
        WAITV(0);          // qq>=6 stagers have no x loads: explicit drain
        WRITE_BS(0, 0)
    }
    LOAD_RING(0, 3)
    BAR();             // Xs(ih0) + Bs(step0) + zero region ready

    STEP(0,4)  STEP(1,4)  STEP(2,4)  STEP(3,4)  STEP(4,4)
    STEP(5,4)  STEP(6,4)  STEP(7,4)  STEP(8,4)

    STAGE_XS(1)        // all half-0 Xs reads completed at STEP(8)'s barrier
    BAR();

    STEP(9,4)   STEP(10,4) STEP(11,4) STEP(12,4) STEP(13,4)
    STEP(14,4)  STEP(15,2) STEP(16,0) STEP(17,0)

    // ---- epilogue: C col = o' = lane&15 (store only o'<8), row = b_local ----
    if (!nhi) {
        const int og = o0 + (lane & 15);
        const int rb = ks_*4;
        #pragma unroll
        for (int dl = 0; dl < 4; ++dl) {
            const int lgl = l0 + lg*4 + dl;
            const float bv = bias[og*SEQ + lgl];
            #pragma unroll
            for (int r = 0; r < 4; ++r) {
                const int bg = bt*16 + rb + r;
                out[((size_t)(bg*COUT + og))*SEQ + lgl] = acc[dl][r] + bv;
            }
        }
    }
}

extern "C" void kernel_launch(void* const* d_in, const int* in_sizes, int n_in,
                              void* d_out, int out_size, void* d_ws, size_t ws_size,
                              hipStream_t stream) {
    const float* x    = (const float*)d_in[0];
    const float* wgt  = (const float*)d_in[1];
    const float* bias = (const float*)d_in[2];
    float* out        = (float*)d_out;

    hipFuncSetAttribute((const void*)lc1d_mfma,
                        hipFuncAttributeMaxDynamicSharedMemorySize, LDS_BYTES);
    dim3 grid(256);   // blockIdx = lt*8 + os: os == XCD id; lt line-mates co-XCD
    lc1d_mfma<<<grid, 1024, LDS_BYTES, stream>>>(x, wgt, bias, out);
}